// Round 14
// baseline (8756.277 us; speedup 1.0000x reference)
//
#include <hip/hip_runtime.h>
#include <cstdint>

constexpr int Bn = 128, Tn = 1024, Dn = 64, Hn = 256, On = 128;

typedef __fp16 h2 __attribute__((ext_vector_type(2)));
typedef __fp16 half8_t __attribute__((ext_vector_type(8)));
typedef float f32x4 __attribute__((ext_vector_type(4)));
typedef unsigned short u16;

__device__ __forceinline__ float fast_tanh(float x) {
  float e = __expf(2.0f * x);
  return 1.0f - 2.0f / (e + 1.0f);
}
__device__ __forceinline__ h2 pk2(float a, float b) {
  h2 r; r.x = (__fp16)a; r.y = (__fp16)b; return r;
}
__device__ __forceinline__ unsigned h2bits(h2 v) { return __builtin_bit_cast(unsigned, v); }
__device__ __forceinline__ u16 f2hb(float f) {
  __fp16 h = (__fp16)f; return __builtin_bit_cast(u16, h);
}
__device__ __forceinline__ float hb2f(u16 b) {
  return (float)__builtin_bit_cast(__fp16, b);
}
// Pin a 4-dword value into the AGPR file. REGISTER MODEL (rounds 7-13):
// AGPRs are allocated ONLY when inline asm is present (mayNeedAGPRs);
// without it the unified 256-reg budget collapses to 128 arch-only and
// a 128-reg weight array spills to SCRATCH (round 13: FETCH 21.9 GB,
// 8.6 ms). With the pin, weights sit in AGPRs and MFMA reads them
// natively (isa §10) -- bit-exact in rounds 10-13.
__device__ __forceinline__ void pinA4(half8_t& w) {
  f32x4 t = __builtin_bit_cast(f32x4, w);
  asm volatile("" : "+a"(t));
  w = __builtin_bit_cast(half8_t, t);
}

// ---------------------------------------------------------------------------
// 4-chain MFMA matvec, K=256, source in the 20-stride slice layout.
// A-frag is the BROADCAST trick (rounds 10/11, absmax-verified): every lane's
// af covers k = 32kt + 8*(l>>4) + e, independent of l&15 -> all 16 rows of A
// equal h -> D reg 0 = h @ W for every lane. A and B use the SAME assumed
// k-map so any intra-tile k-permutation cancels.
// ---------------------------------------------------------------------------
__device__ __forceinline__ void mv256(const u16* base, int oh, int ol,
                                      const half8_t (&wf)[32], float (&v)[4]) {
  uint2 ra[8], rb[8];
  #pragma unroll
  for (int kt = 0; kt < 8; ++kt) {
    const u16* ap = base + 40 * kt + 20 * oh + 8 * ol;
    ra[kt] = *(const uint2*)ap;
    rb[kt] = *(const uint2*)(ap + 4);
  }
  f32x4 a0 = {0.f,0.f,0.f,0.f}, a1 = {0.f,0.f,0.f,0.f},
        a2 = {0.f,0.f,0.f,0.f}, a3 = {0.f,0.f,0.f,0.f};
  #pragma unroll
  for (int kt = 0; kt < 8; ++kt) {
    half8_t af = __builtin_bit_cast(
        half8_t, make_uint4(ra[kt].x, ra[kt].y, rb[kt].x, rb[kt].y));
    a0 = __builtin_amdgcn_mfma_f32_16x16x32_f16(af, wf[kt], a0, 0, 0, 0);
    a1 = __builtin_amdgcn_mfma_f32_16x16x32_f16(af, wf[8 + kt], a1, 0, 0, 0);
    a2 = __builtin_amdgcn_mfma_f32_16x16x32_f16(af, wf[16 + kt], a2, 0, 0, 0);
    a3 = __builtin_amdgcn_mfma_f32_16x16x32_f16(af, wf[24 + kt], a3, 0, 0, 0);
  }
  v[0] = a0[0]; v[1] = a1[0]; v[2] = a2[0]; v[3] = a3[0];
}
// K=64 variant; source row in plain stride-64-half layout, 16B aligned.
// Uses wf[g*8 + kt], kt in {0,1}.
__device__ __forceinline__ void mv64(const u16* xrow, int lq,
                                     const half8_t (&wf)[32], float (&v)[4]) {
  uint4 r0 = *(const uint4*)(xrow + lq);
  uint4 r1 = *(const uint4*)(xrow + 32 + lq);
  half8_t af0 = __builtin_bit_cast(half8_t, r0);
  half8_t af1 = __builtin_bit_cast(half8_t, r1);
  f32x4 a0 = {0.f,0.f,0.f,0.f}, a1 = {0.f,0.f,0.f,0.f},
        a2 = {0.f,0.f,0.f,0.f}, a3 = {0.f,0.f,0.f,0.f};
  a0 = __builtin_amdgcn_mfma_f32_16x16x32_f16(af0, wf[0], a0, 0, 0, 0);
  a0 = __builtin_amdgcn_mfma_f32_16x16x32_f16(af1, wf[1], a0, 0, 0, 0);
  a1 = __builtin_amdgcn_mfma_f32_16x16x32_f16(af0, wf[8], a1, 0, 0, 0);
  a1 = __builtin_amdgcn_mfma_f32_16x16x32_f16(af1, wf[9], a1, 0, 0, 0);
  a2 = __builtin_amdgcn_mfma_f32_16x16x32_f16(af0, wf[16], a2, 0, 0, 0);
  a2 = __builtin_amdgcn_mfma_f32_16x16x32_f16(af1, wf[17], a2, 0, 0, 0);
  a3 = __builtin_amdgcn_mfma_f32_16x16x32_f16(af0, wf[24], a3, 0, 0, 0);
  a3 = __builtin_amdgcn_mfma_f32_16x16x32_f16(af1, wf[25], a3, 0, 0, 0);
  v[0] = a0[0]; v[1] = a1[0]; v[2] = a2[0]; v[3] = a3[0];
}

// LDS h layout (f16): 16 slices x (16 data + 4 pad) halfs; slice stride 40 B.
// ---------------------------------------------------------------------------
// Fused pipeline, 256 WGs x 512 threads (8 waves). Thesis (rounds 12-14):
// serial-step cost tracks BARRIER POPULATION (16-wave: 1.05-1.15 us/step
// regardless of compute path; 8-wave: 0.61-0.78). Wave-specialized:
//   waves 0-3 serial (64 cols each via 4 MFMA chains; W frags pinned AGPR),
//   waves 4-7 dense  (u-rows via same MFMA matvec; row s+1 in slice s).
// waves_per_eu(2,2): our exact occupancy (8 waves/CU) -> 256-reg budget,
// split 128 arch + 128 AGPR by the asm pin. Working set ~60 arch.
//   role A  (blocks 0..127):  serial scan1 (Wh1) + dense u1 = x@Wx1+b1.
//   role BC (blocks 128..255): serial scan2 (Wh2) + dense u2 = h1@Wx2+b2.
// ---------------------------------------------------------------------------
__global__ __launch_bounds__(512)
__attribute__((amdgpu_waves_per_eu(2, 2))) void stage1_kernel(
    const float* __restrict__ x,    // [B,T,64] f32
    const float* __restrict__ Wx1,  // [64,256] f32
    const float* __restrict__ Wh1,  // [256,256] f32
    const float* __restrict__ b1,   // [256]
    const float* __restrict__ Wx2,  // [256,256] f32
    const float* __restrict__ b2,   // [256]
    const float* __restrict__ Wh2,  // [256,256] f32
    u16* __restrict__ h1b16,        // [B,T,256] f16 h1 (A -> BC channel)
    int* __restrict__ flags,        // [B]  A -> BC progress (32-step chunks)
    float* __restrict__ hfinal) {   // [B,256] f32 (role BC output)
  __shared__ alignas(16) u16 smemU[19584];  // 38.25 KB
  const int tid = threadIdx.x;
  const unsigned bid = blockIdx.x;
  const bool roleA = (bid < (unsigned)Bn);
  const int wv = tid >> 6;              // wave 0..7
  const bool serialG = (wv < 4);
  const int l = tid & 63;
  const int oh = (l >> 5) & 1;
  const int ol = (l >> 4) & 1;
  const int lq = 8 * (l >> 4);          // k-oct offset (halfs)
  const int c0 = 64 * (wv & 3);         // wave's column base
  const int lt = tid & 255;             // index within wave-group

  // ---- weights: col c0+16g+(l&15), k = 32kt + lq + e ----
  half8_t wf[32];
  {
    const float* Wsrc = roleA ? (serialG ? Wh1 : Wx1)
                              : (serialG ? Wh2 : Wx2);
    const int kmax = (roleA && !serialG) ? 2 : 8;
    for (int g = 0; g < 4; ++g)
      for (int kt = 0; kt < kmax; ++kt) {
        const float* wp =
            Wsrc + (size_t)(32 * kt + lq) * Hn + c0 + 16 * g + (l & 15);
        half8_t f;
        #pragma unroll
        for (int e = 0; e < 8; ++e) f[e] = (__fp16)wp[(size_t)e * Hn];
        wf[g * 8 + kt] = f;
      }
    // Zero unused slots (role-A dense) so pins don't carry undef.
    if (kmax == 2)
      for (int g = 0; g < 4; ++g)
        for (int kt = 2; kt < 8; ++kt) wf[g * 8 + kt] = half8_t{0};
  }
  #pragma unroll
  for (int i = 0; i < 32; ++i) pinA4(wf[i]);  // -> AGPR file (see pinA4 note)

  if (roleA) {
    // ==================== ROLE A ====================
    const int b = bid;
    const float* xb = x + (size_t)b * Tn * Dn;
    u16* hb = h1b16 + (size_t)b * Tn * Hn;
    u16* hcH = smemU;            // 640 halfs: 2 x 320 h-state
    u16* xs = smemU + 640;       // 2048 halfs: x chunk [32][64] f16
    u16* u1S = smemU + 2688;     // 8704 halfs: u1 [32][272]
    float bj[4];
    if (!serialG) {
      #pragma unroll
      for (int g = 0; g < 4; ++g) bj[g] = b1[c0 + 16 * g + (l & 15)];
    }
    for (int i = tid; i < 640; i += 512) hcH[i] = 0;
    __syncthreads();

    for (int ch = 0; ch < 32; ++ch) {
      if (!serialG) {  // stage x chunk -> xs (f16): thread -> 8 f32
        const float* src = xb + (size_t)ch * 2048 + lt * 8;
        float4 f0 = *(const float4*)src, f1 = *(const float4*)(src + 4);
        *(uint4*)(xs + lt * 8) =
            make_uint4(h2bits(pk2(f0.x, f0.y)), h2bits(pk2(f0.z, f0.w)),
                       h2bits(pk2(f1.x, f1.y)), h2bits(pk2(f1.z, f1.w)));
      }
      __syncthreads();
      if (!serialG) {  // u1 row 0
        float v[4];
        mv64(xs, lq, wf, v);
        if (l < 16) {
          #pragma unroll
          for (int g = 0; g < 4; ++g)
            u1S[c0 + 16 * g + l] = f2hb(v[g] + bj[g]);
        }
      }
      __syncthreads();
      for (int g4 = 0; g4 < 4; ++g4) {
        u16 hr[4][8];
        #pragma unroll
        for (int s8 = 0; s8 < 8; ++s8) {
          const int s = 8 * g4 + s8;
          if (serialG) {
            const int cu = s & 1, nx = cu ^ 1;
            float uv[4];
            #pragma unroll
            for (int g = 0; g < 4; ++g)
              uv[g] = hb2f(u1S[s * 272 + c0 + 16 * g + (l & 15)]);
            float v[4];
            mv256(hcH + cu * 320, oh, ol, wf, v);
            #pragma unroll
            for (int g = 0; g < 4; ++g) {
              u16 hh = f2hb(fast_tanh(v[g] + uv[g]));
              if (l < 16) hcH[nx * 320 + 20 * (4 * wv + g) + l] = hh;
              hr[g][s8] = hh;
            }
            if (s8 == 7 && l < 16) {
              u16* d0 = hb + (size_t)(ch * 32 + 8 * g4) * Hn + c0 + l;
              #pragma unroll
              for (int i = 0; i < 8; ++i)
                #pragma unroll
                for (int g = 0; g < 4; ++g) d0[i * Hn + 16 * g] = hr[g][i];
            }
          } else if (s < 31) {
            float v[4];
            mv64(xs + (s + 1) * 64, lq, wf, v);
            if (l < 16) {
              #pragma unroll
              for (int g = 0; g < 4; ++g)
                u1S[(s + 1) * 272 + c0 + 16 * g + l] = f2hb(v[g] + bj[g]);
            }
          }
          __syncthreads();  // drains vmem (incl. h1 stores at s8==7)
        }
      }
      if (tid == 0)
        __hip_atomic_store(flags + b, ch + 1, __ATOMIC_RELEASE,
                           __HIP_MEMORY_SCOPE_AGENT);
    }
  } else {
    // ==================== ROLE BC ====================
    const int b = bid - Bn;
    const u16* hb1 = h1b16 + (size_t)b * Tn * Hn;
    u16* hsH = smemU;            // [32][320] halfs (h1 staging, slice layout)
    u16* u2S = smemU + 10240;    // [32][272] halfs (u2)
    u16* hcU = smemU + 18944;    // 2 x 320 halfs (h2 state)
    float bj[4];
    if (!serialG) {
      #pragma unroll
      for (int g = 0; g < 4; ++g) bj[g] = b2[c0 + 16 * g + (l & 15)];
    }
    for (int i = tid; i < 640; i += 512) hcU[i] = 0;
    __syncthreads();

    for (int ch = 0; ch < 32; ++ch) {
      if (!serialG && lt == 0) {
        while (__hip_atomic_load(flags + b, __ATOMIC_ACQUIRE,
                                 __HIP_MEMORY_SCOPE_AGENT) < ch + 1)
          __builtin_amdgcn_s_sleep(8);
      }
      __syncthreads();  // flag acquired
      if (!serialG) {
        // stage h1 chunk -> hsH, round-11-verified pattern: 512 slice-tasks
        // (row 0..31 x slice 0..15), 2 per dense thread.
        #pragma unroll
        for (int it = 0; it < 2; ++it) {
          const int idx = lt + 256 * it;        // 0..511
          const int row = idx >> 4, sc = idx & 15;
          const u16* src = hb1 + (size_t)(ch * 32 + row) * Hn + 16 * sc;
          uint4 v0 = ((const uint4*)src)[0], v1 = ((const uint4*)src)[1];
          u16* d = hsH + row * 320 + 20 * sc;
          ((uint2*)d)[0] = make_uint2(v0.x, v0.y);
          ((uint2*)d)[1] = make_uint2(v0.z, v0.w);
          ((uint2*)d)[2] = make_uint2(v1.x, v1.y);
          ((uint2*)d)[3] = make_uint2(v1.z, v1.w);
        }
      }
      __syncthreads();  // staged
      if (!serialG) {   // u2 row 0
        float v[4];
        mv256(hsH, oh, ol, wf, v);
        if (l < 16) {
          #pragma unroll
          for (int g = 0; g < 4; ++g)
            u2S[c0 + 16 * g + l] = f2hb(v[g] + bj[g]);
        }
      }
      __syncthreads();  // row 0 visible

      for (int g4 = 0; g4 < 4; ++g4) {
        #pragma unroll
        for (int s8 = 0; s8 < 8; ++s8) {
          const int s = 8 * g4 + s8;
          if (serialG) {
            const int cu = s & 1, nx = cu ^ 1;
            float uv[4];
            #pragma unroll
            for (int g = 0; g < 4; ++g)
              uv[g] = hb2f(u2S[s * 272 + c0 + 16 * g + (l & 15)]);
            float v[4];
            mv256(hcU + cu * 320, oh, ol, wf, v);
            #pragma unroll
            for (int g = 0; g < 4; ++g) {
              u16 hh = f2hb(fast_tanh(v[g] + uv[g]));
              if (l < 16) hcU[nx * 320 + 20 * (4 * wv + g) + l] = hh;
            }
          } else if (s < 31) {
            float v[4];
            mv256(hsH + (s + 1) * 320, oh, ol, wf, v);
            if (l < 16) {
              #pragma unroll
              for (int g = 0; g < 4; ++g)
                u2S[(s + 1) * 272 + c0 + 16 * g + l] = f2hb(v[g] + bj[g]);
            }
          }
          __syncthreads();
        }
      }
    }
    if (tid < Hn)
      hfinal[(size_t)b * Hn + tid] = hb2f(hcU[(tid >> 4) * 20 + (tid & 15)]);
  }
}

// ---------------------------------------------------------------------------
// Head: out = softmax(h2_T @ Wd + bd). f32, unchanged.
// ---------------------------------------------------------------------------
__global__ __launch_bounds__(128) void head_kernel(
    const float* __restrict__ hfinal, const float* __restrict__ Wd,
    const float* __restrict__ bd, float* __restrict__ out) {
  __shared__ float hrow[Hn];
  __shared__ float red[On];
  const int o = threadIdx.x;
  const int b = blockIdx.x;
  hrow[o] = hfinal[(size_t)b * Hn + o];
  hrow[o + 128] = hfinal[(size_t)b * Hn + 128 + o];
  __syncthreads();
  float acc = bd[o];
  #pragma unroll 8
  for (int k = 0; k < Hn; ++k) acc = fmaf(hrow[k], Wd[(size_t)k * On + o], acc);
  red[o] = acc;
  __syncthreads();
  #pragma unroll
  for (int s = 64; s > 0; s >>= 1) {
    if (o < s) red[o] = fmaxf(red[o], red[o + s]);
    __syncthreads();
  }
  const float mx = red[0];
  __syncthreads();
  const float e = __expf(acc - mx);
  red[o] = e;
  __syncthreads();
  #pragma unroll
  for (int s = 64; s > 0; s >>= 1) {
    if (o < s) red[o] += red[o + s];
    __syncthreads();
  }
  out[(size_t)b * On + o] = e / red[0];
}

// ---------------------------------------------------------------------------
extern "C" void kernel_launch(void* const* d_in, const int* in_sizes, int n_in,
                              void* d_out, int out_size, void* d_ws, size_t ws_size,
                              hipStream_t stream) {
  const float* x   = (const float*)d_in[0];
  const float* Wx1 = (const float*)d_in[1];
  const float* Wh1 = (const float*)d_in[2];
  const float* b1  = (const float*)d_in[3];
  const float* Wx2 = (const float*)d_in[4];
  const float* Wh2 = (const float*)d_in[5];
  const float* b2  = (const float*)d_in[6];
  const float* Wd  = (const float*)d_in[7];
  const float* bd  = (const float*)d_in[8];
  float* out = (float*)d_out;

  u16* h1b16 = (u16*)d_ws;                            // [B,T,256] f16 (64 MB)
  float* hfinal = (float*)(h1b16 + (size_t)Bn * Tn * Hn);  // [B,256] f32
  int* flags = (int*)(hfinal + (size_t)Bn * Hn);      // [B] A->BC

  hipMemsetAsync(flags, 0, Bn * sizeof(int), stream);
  stage1_kernel<<<2 * Bn, 512, 0, stream>>>(x, Wx1, Wh1, b1, Wx2, b2, Wh2,
                                            h1b16, flags, hfinal);
  head_kernel<<<Bn, 128, 0, stream>>>(hfinal, Wd, bd, out);
}

// Round 15
// 1078.671 us; speedup vs baseline: 8.1177x; 8.1177x over previous
//
#include <hip/hip_runtime.h>
#include <cstdint>

constexpr int Bn = 128, Tn = 1024, Dn = 64, Hn = 256, On = 128;

typedef __fp16 h2 __attribute__((ext_vector_type(2)));
typedef __fp16 half8_t __attribute__((ext_vector_type(8)));
typedef float f32x4 __attribute__((ext_vector_type(4)));
typedef unsigned short u16;

__device__ __forceinline__ float fast_tanh(float x) {
  float e = __expf(2.0f * x);
  return 1.0f - 2.0f / (e + 1.0f);
}
__device__ __forceinline__ float fdot2(h2 a, h2 b, float c) {
#if __has_builtin(__builtin_amdgcn_fdot2)
  return __builtin_amdgcn_fdot2(a, b, c, false);
#else
  return fmaf((float)a.y, (float)b.y, fmaf((float)a.x, (float)b.x, c));
#endif
}
__device__ __forceinline__ h2 pk2(float a, float b) {
  h2 r; r.x = (__fp16)a; r.y = (__fp16)b; return r;
}
__device__ __forceinline__ h2 bits2h(unsigned u) { return __builtin_bit_cast(h2, u); }
__device__ __forceinline__ unsigned h2bits(h2 v) { return __builtin_bit_cast(unsigned, v); }
__device__ __forceinline__ u16 f2hb(float f) {
  __fp16 h = (__fp16)f; return __builtin_bit_cast(u16, h);
}
__device__ __forceinline__ float hb2f(u16 b) {
  return (float)__builtin_bit_cast(__fp16, b);
}

template <int CTRL>
__device__ __forceinline__ float dpp_add(float v) {
  int s = __builtin_amdgcn_update_dpp(0, __float_as_int(v), CTRL, 0xF, 0xF, true);
  return v + __int_as_float(s);
}
__device__ __forceinline__ float row16_sum(float v) {
  v = dpp_add<0xB1>(v);   // quad_perm xor1
  v = dpp_add<0x4E>(v);   // quad_perm xor2
  v = dpp_add<0x141>(v);  // xor4
  v = dpp_add<0x140>(v);  // xor8
  return v;
}
__device__ __forceinline__ float sel8(int ks, float s0, float s1, float s2,
                                      float s3, float s4, float s5, float s6,
                                      float s7) {
  float u0 = (ks & 1) ? s1 : s0;
  float u1 = (ks & 1) ? s3 : s2;
  float u2 = (ks & 1) ? s5 : s4;
  float u3 = (ks & 1) ? s7 : s6;
  float v0 = (ks & 2) ? u1 : u0;
  float v1 = (ks & 2) ? u3 : u2;
  return (ks & 4) ? v1 : v0;
}

// ---------------------------------------------------------------------------
// Dense matvec helpers (v_dot path, throughput waves). Weights packed
// 4 k-pairs per half8_t slot. AGPR residency + accvgpr_read cost fine here.
// ---------------------------------------------------------------------------
__device__ __forceinline__ float dense_row256(const u16* rowbase, int ks,
                                              const half8_t (&wfr)[16]) {
  const uint2* hq = (const uint2*)(rowbase + 20 * ks);
  uint2 q0 = hq[0], q1 = hq[1], q2 = hq[2], q3 = hq[3];
  float a0 = 0.f, a1 = 0.f, a2 = 0.f, a3 = 0.f,
        a4 = 0.f, a5 = 0.f, a6 = 0.f, a7 = 0.f;
  const unsigned d[8] = {q0.x, q0.y, q1.x, q1.y, q2.x, q2.y, q3.x, q3.y};
  #pragma unroll
  for (int p = 0; p < 8; ++p) {
    h2 hp = bits2h(d[p]);
    uint4 lo = __builtin_bit_cast(uint4, wfr[p]);
    uint4 hi = __builtin_bit_cast(uint4, wfr[p + 8]);
    a0 = fdot2(hp, bits2h(lo.x), a0);
    a1 = fdot2(hp, bits2h(lo.y), a1);
    a2 = fdot2(hp, bits2h(lo.z), a2);
    a3 = fdot2(hp, bits2h(lo.w), a3);
    a4 = fdot2(hp, bits2h(hi.x), a4);
    a5 = fdot2(hp, bits2h(hi.y), a5);
    a6 = fdot2(hp, bits2h(hi.z), a6);
    a7 = fdot2(hp, bits2h(hi.w), a7);
  }
  float s0 = row16_sum(a0), s1 = row16_sum(a1);
  float s2 = row16_sum(a2), s3 = row16_sum(a3);
  float s4 = row16_sum(a4), s5 = row16_sum(a5);
  float s6 = row16_sum(a6), s7 = row16_sum(a7);
  return sel8(ks, s0, s1, s2, s3, s4, s5, s6, s7);
}
// K=64 variant for u1 = x@Wx1 (x row in plain [64]-half layout).
__device__ __forceinline__ float dense_row64(const u16* xrow, int ks,
                                             const half8_t (&wfr)[16]) {
  uint2 xq = *(const uint2*)(xrow + 4 * ks);
  h2 xp0 = bits2h(xq.x), xp1 = bits2h(xq.y);
  uint4 lo0 = __builtin_bit_cast(uint4, wfr[0]);
  uint4 lo1 = __builtin_bit_cast(uint4, wfr[1]);
  uint4 hi0 = __builtin_bit_cast(uint4, wfr[8]);
  uint4 hi1 = __builtin_bit_cast(uint4, wfr[9]);
  float a0 = 0.f, a1 = 0.f, a2 = 0.f, a3 = 0.f,
        a4 = 0.f, a5 = 0.f, a6 = 0.f, a7 = 0.f;
  a0 = fdot2(xp0, bits2h(lo0.x), a0); a0 = fdot2(xp1, bits2h(lo1.x), a0);
  a1 = fdot2(xp0, bits2h(lo0.y), a1); a1 = fdot2(xp1, bits2h(lo1.y), a1);
  a2 = fdot2(xp0, bits2h(lo0.z), a2); a2 = fdot2(xp1, bits2h(lo1.z), a2);
  a3 = fdot2(xp0, bits2h(lo0.w), a3); a3 = fdot2(xp1, bits2h(lo1.w), a3);
  a4 = fdot2(xp0, bits2h(hi0.x), a4); a4 = fdot2(xp1, bits2h(hi1.x), a4);
  a5 = fdot2(xp0, bits2h(hi0.y), a5); a5 = fdot2(xp1, bits2h(hi1.y), a5);
  a6 = fdot2(xp0, bits2h(hi0.z), a6); a6 = fdot2(xp1, bits2h(hi1.z), a6);
  a7 = fdot2(xp0, bits2h(hi0.w), a7); a7 = fdot2(xp1, bits2h(hi1.w), a7);
  float s0 = row16_sum(a0), s1 = row16_sum(a1);
  float s2 = row16_sum(a2), s3 = row16_sum(a3);
  float s4 = row16_sum(a4), s5 = row16_sum(a5);
  float s6 = row16_sum(a6), s7 = row16_sum(a7);
  return sel8(ks, s0, s1, s2, s3, s4, s5, s6, s7);
}

// ---------------------------------------------------------------------------
// MFMA serial matvec with prefetched A-fragments (round-11, 1081us verified).
// B-frags (weights) live in AGPRs (natural 64/64 split at 1024 threads);
// MFMA reads them natively (isa §10). Broadcast A-frag trick: D reg 0 =
// h @ W for lanes 0-15 columns; A,B share the same k-map so any intra-tile
// k-permutation cancels (absmax-verified rounds 10-14).
// ---------------------------------------------------------------------------
__device__ __forceinline__ void mfma_step(const u16* hcB, int oh, int ol,
                                          const half8_t (&wfr)[16],
                                          float& v0, float& v1) {
  uint2 ra[8], rb[8];
  #pragma unroll
  for (int kt = 0; kt < 8; ++kt) {
    const u16* ap = hcB + 40 * kt + 20 * oh + 8 * ol;
    ra[kt] = *(const uint2*)ap;
    rb[kt] = *(const uint2*)(ap + 4);
  }
  f32x4 ac0 = {0.f, 0.f, 0.f, 0.f}, ac1 = {0.f, 0.f, 0.f, 0.f};
  #pragma unroll
  for (int kt = 0; kt < 8; ++kt) {
    half8_t af = __builtin_bit_cast(
        half8_t, make_uint4(ra[kt].x, ra[kt].y, rb[kt].x, rb[kt].y));
    ac0 = __builtin_amdgcn_mfma_f32_16x16x32_f16(af, wfr[kt], ac0, 0, 0, 0);
    ac1 = __builtin_amdgcn_mfma_f32_16x16x32_f16(af, wfr[8 + kt], ac1, 0, 0, 0);
  }
  v0 = ac0[0];
  v1 = ac1[0];
}

// LDS h layout (f16): 16 slices x (16 data + 4 pad) halfs; slice stride 40 B.
// ---------------------------------------------------------------------------
// Fused pipeline, 256 WGs x 1024 threads == 1 block/CU. This is the round-11
// kernel (best passing, 1081 us) + ONE change: T5 s_setprio(1) on serial
// waves, set once at entry (wave priority is persistent state). Mechanism:
// each SIMD hosts 2 serial + 2 dense waves; priority makes the latency-
// critical serial chain win issue arbitration on the MFMA/LDS pipes; dense
// waves have ~3x slack per slice so deprioritizing them is free. Catalog:
// +21-39% on role-split schedules (m218b/m224), null only in lockstep
// (m190) -- ours is role-split.
//   role A  (blocks 0..127): waves 0-7 serial scan1 via MFMA (Wh1 in AGPR);
//       waves 8-15 dense: stage x + u1 = x@Wx1+b1 rows (row s+1 in slice s).
//   role BC (blocks 128..255): waves 0-7 serial scan2 via MFMA (Wh2);
//       waves 8-15 dense u2 = h1@Wx2+b2.
//   wfr[16] unioned (64 regs) to match the 1024-thr 64/64 arch/AGPR split.
// ---------------------------------------------------------------------------
__global__ __launch_bounds__(1024)
__attribute__((amdgpu_waves_per_eu(4, 4))) void stage1_kernel(
    const float* __restrict__ x,    // [B,T,64] f32
    const float* __restrict__ Wx1,  // [64,256] f32
    const float* __restrict__ Wh1,  // [256,256] f32
    const float* __restrict__ b1,   // [256]
    const float* __restrict__ Wx2,  // [256,256] f32
    const float* __restrict__ b2,   // [256]
    const float* __restrict__ Wh2,  // [256,256] f32
    u16* __restrict__ h1b16,        // [B,T,256] f16 h1 (A -> BC channel)
    int* __restrict__ flags,        // [B]  A -> BC progress (32-step chunks)
    float* __restrict__ hfinal) {   // [B,256] f32 (role BC output)
  __shared__ alignas(16) u16 smemU[19584];  // 38.25 KB
  const int tid = threadIdx.x;
  const unsigned bid = blockIdx.x;
  const bool roleA = (bid < (unsigned)Bn);
  const bool serialG = (tid < 512);

  // T5: serial waves get persistent priority 1 (dense stay at 0).
  if (serialG) __builtin_amdgcn_s_setprio(1);

  // ---- common index math ----
  // serial lanes:
  const int w_ = tid >> 6;          // wave 0..7
  const int l = tid & 63;
  const int oh = (l >> 5) & 1;      // k-oct high bit
  const int ol = (l >> 4) & 1;      // k-oct low bit
  const int jc = 32 * w_ + (l & 15);  // colgroup-0 column
  const int woff0 = 40 * w_ + (l & 15);
  // dense lanes:
  const int lt = tid & 511;
  const int ks = lt & 15;
  const int cg = lt >> 4;
  const int col0 = 8 * cg;
  const int jcol = col0 + (ks & 7);
  const bool writerD = (ks < 8);

  half8_t wfr[16];  // union: serial B-frags OR dense packed k-pairs

  if (serialG) {
    // Serial weights: B-frag (g,kt): lane l holds W[32kt+8(l>>4)+e][32w+16g+(l&15)]
    const float* Wser = roleA ? Wh1 : Wh2;
    const int ko = 8 * (l >> 4);
    #pragma unroll
    for (int g = 0; g < 2; ++g)
      #pragma unroll
      for (int kt = 0; kt < 8; ++kt) {
        const float* wp = Wser + (size_t)(32 * kt + ko) * Hn + jc + 16 * g;
        half8_t f;
        #pragma unroll
        for (int e = 0; e < 8; ++e) f[e] = (__fp16)wp[(size_t)e * Hn];
        wfr[g * 8 + kt] = f;
      }
  } else if (roleA) {
    // Dense-A weights: Wx1 k-pairs (4ks+2p,+1) x 8 cols, packed (p=0..1)
    #pragma unroll
    for (int p = 0; p < 2; ++p) {
      const float* r0 = Wx1 + (size_t)(4 * ks + 2 * p) * Hn + col0;
      float4 a0 = *(const float4*)r0, a1 = *(const float4*)(r0 + 4);
      float4 c0 = *(const float4*)(r0 + Hn), c1 = *(const float4*)(r0 + Hn + 4);
      wfr[p] = __builtin_bit_cast(half8_t,
          make_uint4(h2bits(pk2(a0.x, c0.x)), h2bits(pk2(a0.y, c0.y)),
                     h2bits(pk2(a0.z, c0.z)), h2bits(pk2(a0.w, c0.w))));
      wfr[p + 8] = __builtin_bit_cast(half8_t,
          make_uint4(h2bits(pk2(a1.x, c1.x)), h2bits(pk2(a1.y, c1.y)),
                     h2bits(pk2(a1.z, c1.z)), h2bits(pk2(a1.w, c1.w))));
    }
  } else {
    // Dense-BC weights: Wx2 k-pairs (16ks+2p,+1) x 8 cols, packed (p=0..7)
    #pragma unroll
    for (int p = 0; p < 8; ++p) {
      const float* r0 = Wx2 + (size_t)(16 * ks + 2 * p) * Hn + col0;
      float4 a0 = *(const float4*)r0, a1 = *(const float4*)(r0 + 4);
      float4 c0 = *(const float4*)(r0 + Hn), c1 = *(const float4*)(r0 + Hn + 4);
      wfr[p] = __builtin_bit_cast(half8_t,
          make_uint4(h2bits(pk2(a0.x, c0.x)), h2bits(pk2(a0.y, c0.y)),
                     h2bits(pk2(a0.z, c0.z)), h2bits(pk2(a0.w, c0.w))));
      wfr[p + 8] = __builtin_bit_cast(half8_t,
          make_uint4(h2bits(pk2(a1.x, c1.x)), h2bits(pk2(a1.y, c1.y)),
                     h2bits(pk2(a1.z, c1.z)), h2bits(pk2(a1.w, c1.w))));
    }
  }

  if (roleA) {
    // ==================== ROLE A ====================
    const int b = bid;
    const float* xb = x + (size_t)b * Tn * Dn;
    u16* hb = h1b16 + (size_t)b * Tn * Hn;
    u16* hcH = smemU;            // 640 halfs: 2 x 320 h-state
    u16* xs = smemU + 640;       // 2048 halfs: x chunk [32][64] f16
    u16* u1S = smemU + 2688;     // 8704 halfs: u1 [32][272]
    const float bj = b1[jcol];   // dense bias

    if (serialG)
      for (int i = tid; i < 640; i += 512) hcH[i] = 0;
    __syncthreads();

    for (int ch = 0; ch < 32; ++ch) {
      // pre1: dense stages x chunk ch -> xs (f16)
      if (!serialG) {
        const float* xsrc = xb + (size_t)ch * 2048 + (lt >> 4) * 64 + (lt & 15) * 4;
        float4 f = *(const float4*)xsrc;
        *(uint2*)(xs + (lt >> 4) * 64 + (lt & 15) * 4) =
            make_uint2(h2bits(pk2(f.x, f.y)), h2bits(pk2(f.z, f.w)));
      }
      __syncthreads();
      // pre2: dense computes u1 row 0
      if (!serialG) {
        float v = dense_row64(xs, ks, wfr);
        if (writerD) u1S[jcol] = f2hb(v + bj);
      }
      __syncthreads();
      // 32 slices: serial step s || dense u1 row s+1
      for (int g4 = 0; g4 < 4; ++g4) {
        u16 hreg0[8], hreg1[8];
        #pragma unroll
        for (int s8 = 0; s8 < 8; ++s8) {
          const int s = g4 * 8 + s8;
          if (serialG) {
            const int cu = s & 1, nx = cu ^ 1;
            float uv0 = hb2f(u1S[s * 272 + jc]);
            float uv1 = hb2f(u1S[s * 272 + jc + 16]);
            float v0, v1;
            mfma_step(hcH + cu * 320, oh, ol, wfr, v0, v1);
            u16 h0 = f2hb(fast_tanh(v0 + uv0));
            u16 h1 = f2hb(fast_tanh(v1 + uv1));
            if (l < 16) {
              hcH[nx * 320 + woff0] = h0;
              hcH[nx * 320 + woff0 + 20] = h1;
            }
            hreg0[s8] = h0;
            hreg1[s8] = h1;
            if (s8 == 7 && l < 16) {
              u16* d0 = hb + (size_t)(32 * ch + s - 7) * Hn + jc;
              #pragma unroll
              for (int i = 0; i < 8; ++i) {
                d0[i * Hn] = hreg0[i];
                d0[i * Hn + 16] = hreg1[i];
              }
            }
          } else if (s < 31) {
            float v = dense_row64(xs + (s + 1) * 64, ks, wfr);
            if (writerD) u1S[(s + 1) * 272 + jcol] = f2hb(v + bj);
          }
          __syncthreads();  // drains vmem (incl. h1 stores at s8==7)
        }
      }
      if (tid == 0)
        __hip_atomic_store(flags + b, ch + 1, __ATOMIC_RELEASE,
                           __HIP_MEMORY_SCOPE_AGENT);
    }
  } else {
    // ==================== ROLE BC ====================
    const int b = bid - Bn;
    const u16* hb1 = h1b16 + (size_t)b * Tn * Hn;
    u16* hsH = smemU;            // [32][320] halfs (h1 staging)
    u16* u2S = smemU + 10240;    // [32][272] halfs (u2)
    u16* hcU = smemU + 18944;    // 2 x 320 halfs (h2 state)
    const float bj = b2[jcol];   // dense bias
    u16* ldst = hsH + (lt >> 4) * 320 + 20 * (lt & 15);

    if (serialG)
      for (int i = tid; i < 640; i += 512) hcU[i] = 0;
    __syncthreads();

    for (int ch = 0; ch < 32; ++ch) {
      if (!serialG && lt == 0) {
        while (__hip_atomic_load(flags + b, __ATOMIC_ACQUIRE,
                                 __HIP_MEMORY_SCOPE_AGENT) < ch + 1)
          __builtin_amdgcn_s_sleep(8);
      }
      __syncthreads();  // flag acquired
      if (!serialG) {   // stage h1 chunk [32][256] -> hsH (slice layout)
        const uint4* src =
            (const uint4*)(hb1 + (size_t)(ch * 32 + (lt >> 4)) * Hn + 16 * (lt & 15));
        uint4 v0 = src[0], v1 = src[1];
        ((uint2*)ldst)[0] = make_uint2(v0.x, v0.y);
        ((uint2*)ldst)[1] = make_uint2(v0.z, v0.w);
        ((uint2*)ldst)[2] = make_uint2(v1.x, v1.y);
        ((uint2*)ldst)[3] = make_uint2(v1.z, v1.w);
      }
      __syncthreads();  // staged
      if (!serialG) {   // u2 row 0
        float v = dense_row256(hsH, ks, wfr);
        if (writerD) u2S[jcol] = f2hb(v + bj);
      }
      __syncthreads();  // row 0 visible

      for (int g4 = 0; g4 < 4; ++g4) {
        #pragma unroll
        for (int s8 = 0; s8 < 8; ++s8) {
          const int s = g4 * 8 + s8;
          if (serialG) {
            const int cu = s & 1, nx = cu ^ 1;
            float uv0 = hb2f(u2S[s * 272 + jc]);
            float uv1 = hb2f(u2S[s * 272 + jc + 16]);
            float v0, v1;
            mfma_step(hcU + cu * 320, oh, ol, wfr, v0, v1);
            if (l < 16) {
              hcU[nx * 320 + woff0] = f2hb(fast_tanh(v0 + uv0));
              hcU[nx * 320 + woff0 + 20] = f2hb(fast_tanh(v1 + uv1));
            }
          } else if (s < 31) {
            float v = dense_row256(hsH + (s + 1) * 320, ks, wfr);
            if (writerD) u2S[(s + 1) * 272 + jcol] = f2hb(v + bj);
          }
          __syncthreads();
        }
      }
    }
    if (tid < Hn)
      hfinal[(size_t)b * Hn + tid] = hb2f(hcU[(tid >> 4) * 20 + (tid & 15)]);
  }
}

// ---------------------------------------------------------------------------
// Head: out = softmax(h2_T @ Wd + bd). f32, unchanged.
// ---------------------------------------------------------------------------
__global__ __launch_bounds__(128) void head_kernel(
    const float* __restrict__ hfinal, const float* __restrict__ Wd,
    const float* __restrict__ bd, float* __restrict__ out) {
  __shared__ float hrow[Hn];
  __shared__ float red[On];
  const int o = threadIdx.x;
  const int b = blockIdx.x;
  hrow[o] = hfinal[(size_t)b * Hn + o];
  hrow[o + 128] = hfinal[(size_t)b * Hn + 128 + o];
  __syncthreads();
  float acc = bd[o];
  #pragma unroll 8
  for (int k = 0; k < Hn; ++k) acc = fmaf(hrow[k], Wd[(size_t)k * On + o], acc);
  red[o] = acc;
  __syncthreads();
  #pragma unroll
  for (int s = 64; s > 0; s >>= 1) {
    if (o < s) red[o] = fmaxf(red[o], red[o + s]);
    __syncthreads();
  }
  const float mx = red[0];
  __syncthreads();
  const float e = __expf(acc - mx);
  red[o] = e;
  __syncthreads();
  #pragma unroll
  for (int s = 64; s > 0; s >>= 1) {
    if (o < s) red[o] += red[o + s];
    __syncthreads();
  }
  out[(size_t)b * On + o] = e / red[0];
}

// ---------------------------------------------------------------------------
extern "C" void kernel_launch(void* const* d_in, const int* in_sizes, int n_in,
                              void* d_out, int out_size, void* d_ws, size_t ws_size,
                              hipStream_t stream) {
  const float* x   = (const float*)d_in[0];
  const float* Wx1 = (const float*)d_in[1];
  const float* Wh1 = (const float*)d_in[2];
  const float* b1  = (const float*)d_in[3];
  const float* Wx2 = (const float*)d_in[4];
  const float* Wh2 = (const float*)d_in[5];
  const float* b2  = (const float*)d_in[6];
  const float* Wd  = (const float*)d_in[7];
  const float* bd  = (const float*)d_in[8];
  float* out = (float*)d_out;

  u16* h1b16 = (u16*)d_ws;                            // [B,T,256] f16 (64 MB)
  float* hfinal = (float*)(h1b16 + (size_t)Bn * Tn * Hn);  // [B,256] f32
  int* flags = (int*)(hfinal + (size_t)Bn * Hn);      // [B] A->BC

  hipMemsetAsync(flags, 0, Bn * sizeof(int), stream);
  stage1_kernel<<<2 * Bn, 1024, 0, stream>>>(x, Wx1, Wh1, b1, Wx2, b2, Wh2,
                                             h1b16, flags, hfinal);
  head_kernel<<<Bn, 128, 0, stream>>>(hfinal, Wd, bd, out);
}